// Round 10
// baseline (532.944 us; speedup 1.0000x reference)
//
#include <hip/hip_runtime.h>
#include <hip/hip_bf16.h>
#include <math.h>

#define BB 4
#define VV 1024
#define HH 128
#define H2 64
#define EE 523776               // V*(V-1)/2
#define BE (BB * EE)            // 2095104
#define NTHR 256
#define NBLK 1024               // 4096 waves: one (b,i) per wave
#define PQN (BB * VV * HH)      // 524288 P entries (and 524288 Q)

typedef __attribute__((ext_vector_type(8))) short bf16x8;
typedef __attribute__((ext_vector_type(4))) float f32x4;
typedef __attribute__((ext_vector_type(4))) unsigned u32x4;

__device__ __forceinline__ short f2bf(float f) {
    __hip_bfloat16 h = __float2bfloat16(f);
    return *reinterpret_cast<short*>(&h);
}

// ONE v_perm_b32: pack two f32 into bf16x2 by truncation (lo -> low half).
__device__ __forceinline__ unsigned pkbf(float lo, float hi) {
    return __builtin_amdgcn_perm(__float_as_uint(hi), __float_as_uint(lo),
                                 0x07060302u);
}

// ---------------------------------------------------------------------------
// Kernel 1: per-vertex precompute.  P[v][h] = W1[0:3,h]·vert, Q[v][h] =
// W1[3:6,h]·vert + b1[h].  Then h1(i,j) = relu(P[i]+Q[j]) exactly replaces
// layer 1 (bias included), removing 16 MFMAs/pair + gather + decode from the
// hot kernel.
// ---------------------------------------------------------------------------
__global__ __launch_bounds__(NTHR) void pq_kernel(
    const float* __restrict__ vertices, const float* __restrict__ W1,
    const float* __restrict__ b1, float* __restrict__ P, float* __restrict__ Q)
{
    const int t = blockIdx.x * NTHR + threadIdx.x;   // 0..PQN-1, exact grid
    const int v = t >> 7;            // global vertex 0..4095
    const int h = t & 127;
    const float x = vertices[v * 3 + 0];
    const float y = vertices[v * 3 + 1];
    const float z = vertices[v * 3 + 2];
    P[t] = x * W1[0 * HH + h] + y * W1[1 * HH + h] + z * W1[2 * HH + h];
    Q[t] = x * W1[3 * HH + h] + y * W1[4 * HH + h] + z * W1[5 * HH + h] + b1[h];
}

// ---------------------------------------------------------------------------
// Kernel 2: one (b,i) per wave; loop jb over j-tiles of 16 (starting past the
// diagonal: zero wasted tiles).  Per tile: build h1 frags from P[i]+Q[j]
// (f32 adds + relu + truncation pack), 16 L2 MFMAs (A2 resident in 64 regs,
// row-permuted so D-layout == L3 B-frag layout), 2 L3 MFMAs (w3 broadcast
// A-frag from LDS, b2 C-init from LDS).  Total regs target < 128 so 4
// waves/SIMD fit (every prior round was capped at 2 by AGPR-resident state).
// ---------------------------------------------------------------------------
__global__ __launch_bounds__(NTHR, 4) void edge_pq(
    const float* __restrict__ P,      // [4096,128] f32
    const float* __restrict__ Q,      // [4096,128] f32
    const float* __restrict__ W2,     // [128,64]
    const float* __restrict__ b2,     // [64]
    const float* __restrict__ W3,     // [64]
    const float* __restrict__ b3,     // [1]
    float* __restrict__ out)          // [BE probs][2*EE indices-as-float]
{
    __shared__ __align__(16) f32x4  cini[4 * 64];   // 4 KB  b2 C-init frags
    __shared__ __align__(16) bf16x8 wA3[2 * 64];    // 2 KB  w3 A-frags

    const int lane = threadIdx.x & 63;
    const int col  = lane & 15;       // edge slot within j-tile
    const int u    = lane >> 4;
    const int wid  = threadIdx.x >> 6;

    // ---- A2 in registers: A2r[mt*4+p] row m -> n2 = 32*(mt>>1) + 8*(m>>2)
    //      + 4*(mt&1) + (m&3); element r -> k = h = 32p + 8u + r.
    //      This row permutation makes L2's D output land exactly in L3's
    //      B-fragment slots (k3 = 32t+8u+r == n2 logical).
    bf16x8 A2r[16];
#pragma unroll
    for (int mt = 0; mt < 4; ++mt) {
        const int n2 = 32 * (mt >> 1) + 8 * (col >> 2) + 4 * (mt & 1) + (col & 3);
#pragma unroll
        for (int p = 0; p < 4; ++p) {
#pragma unroll
            for (int r = 0; r < 8; ++r)
                A2r[mt * 4 + p][r] = f2bf(W2[(32 * p + 8 * u + r) * H2 + n2]);
        }
    }

    // ---- LDS: b2 C-init (per-lane f32x4, q-comp = b2[n2l(mt,u,q)]) and
    //      w3 A-frags (uniform across col: A3[t][r] = W3[32t+8u+r]).
    if (wid == 0) {
#pragma unroll
        for (int mt = 0; mt < 4; ++mt) {
            f32x4 c;
#pragma unroll
            for (int q = 0; q < 4; ++q)
                c[q] = b2[32 * (mt >> 1) + 8 * u + 4 * (mt & 1) + q];
            cini[mt * 64 + lane] = c;
        }
    } else if (wid == 1) {
#pragma unroll
        for (int t = 0; t < 2; ++t) {
            bf16x8 a;
#pragma unroll
            for (int r = 0; r < 8; ++r) a[r] = f2bf(W3[32 * t + 8 * u + r]);
            wA3[t * 64 + lane] = a;
        }
    }
    const float b3v = b3[0];
    __syncthreads();

    const int w = blockIdx.x * 4 + wid;   // 0..4095
    const int b = w >> 10;
    const int i = w & 1023;

    const float* Pi = P + ((b << 10) + i) * HH;
    const int ebase = (i * (2 * VV - 1 - i)) >> 1;   // triangular row start
    float* const probout = out + b * EE + ebase - (i + 1);   // + j indexes it
    float* const idxout  = out + BE;

    const f32x4 zero4 = {0.f, 0.f, 0.f, 0.f};
    (void)zero4;

    for (int jb = (i + 1) >> 4; jb < 64; ++jb) {
        const int j = (jb << 4) + col;
        const float* Qj = Q + ((b << 10) + (jb << 4) + col) * HH;

        // ---- h1 B-frags: relu(P[i]+Q[j]) truncation-packed, 4 k-tiles ----
        bf16x8 Bf[4];
#pragma unroll
        for (int p = 0; p < 4; ++p) {
            const float4 pa = *(const float4*)(Pi + 32 * p + 8 * u);
            const float4 pb = *(const float4*)(Pi + 32 * p + 8 * u + 4);
            const float4 qa = *(const float4*)(Qj + 32 * p + 8 * u);
            const float4 qb = *(const float4*)(Qj + 32 * p + 8 * u + 4);
            u32x4 rr;
            rr[0] = pkbf(fmaxf(pa.x + qa.x, 0.f), fmaxf(pa.y + qa.y, 0.f));
            rr[1] = pkbf(fmaxf(pa.z + qa.z, 0.f), fmaxf(pa.w + qa.w, 0.f));
            rr[2] = pkbf(fmaxf(pb.x + qb.x, 0.f), fmaxf(pb.y + qb.y, 0.f));
            rr[3] = pkbf(fmaxf(pb.z + qb.z, 0.f), fmaxf(pb.w + qb.w, 0.f));
            Bf[p] = __builtin_bit_cast(bf16x8, rr);
        }

        // ---- layer 2: 16 MFMA, C-init = b2 from LDS ----
        f32x4 d2[4];
#pragma unroll
        for (int mt = 0; mt < 4; ++mt) d2[mt] = cini[mt * 64 + lane];
#pragma unroll
        for (int p = 0; p < 4; ++p) {
#pragma unroll
            for (int mt = 0; mt < 4; ++mt)
                d2[mt] = __builtin_amdgcn_mfma_f32_16x16x32_bf16(
                    A2r[mt * 4 + p], Bf[p], d2[mt], 0, 0, 0);
        }

        // ---- layer 3 as MFMA: relu(d2) -> B-frags (layout matches by A2
        //      row permutation), A = w3 broadcast, C-init = b3 ----
        bf16x8 Bh3[2];
#pragma unroll
        for (int t = 0; t < 2; ++t) {
            u32x4 rr;
            rr[0] = pkbf(fmaxf(d2[2 * t][0], 0.f), fmaxf(d2[2 * t][1], 0.f));
            rr[1] = pkbf(fmaxf(d2[2 * t][2], 0.f), fmaxf(d2[2 * t][3], 0.f));
            rr[2] = pkbf(fmaxf(d2[2 * t + 1][0], 0.f), fmaxf(d2[2 * t + 1][1], 0.f));
            rr[3] = pkbf(fmaxf(d2[2 * t + 1][2], 0.f), fmaxf(d2[2 * t + 1][3], 0.f));
            Bh3[t] = __builtin_bit_cast(bf16x8, rr);
        }
        f32x4 d3 = {b3v, b3v, b3v, b3v};
        d3 = __builtin_amdgcn_mfma_f32_16x16x32_bf16(wA3[0 * 64 + lane], Bh3[0], d3, 0, 0, 0);
        d3 = __builtin_amdgcn_mfma_f32_16x16x32_bf16(wA3[1 * 64 + lane], Bh3[1], d3, 0, 0, 0);
        // every row of D equals the w3 dot for edge col; take reg 0.

        if (u == 0 && j > i) {
            const float prob = __builtin_amdgcn_rcpf(1.0f + __expf(-d3[0]));
            probout[j] = prob;                  // e = ebase + j - i - 1
            if (b == 0) {
                const int e = ebase + j - i - 1;
                *(float2*)(&idxout[2 * e]) = make_float2((float)i, (float)j);
            }
        }
    }
}

extern "C" void kernel_launch(void* const* d_in, const int* in_sizes, int n_in,
                              void* d_out, int out_size, void* d_ws, size_t ws_size,
                              hipStream_t stream) {
    const float* vertices = (const float*)d_in[0];
    const float* W1 = (const float*)d_in[1];
    const float* b1 = (const float*)d_in[2];
    const float* W2 = (const float*)d_in[3];
    const float* b2 = (const float*)d_in[4];
    const float* W3 = (const float*)d_in[5];
    const float* b3 = (const float*)d_in[6];
    float* out = (float*)d_out;

    float* P = (float*)d_ws;            // 2 MB
    float* Q = P + PQN;                 // 2 MB  (requires ws_size >= 4 MB)

    pq_kernel<<<PQN / NTHR, NTHR, 0, stream>>>(vertices, W1, b1, P, Q);
    edge_pq<<<NBLK, NTHR, 0, stream>>>(P, Q, W2, b2, W3, b3, out);
}

// Round 11
// 136.538 us; speedup vs baseline: 3.9033x; 3.9033x over previous
//
#include <hip/hip_runtime.h>
#include <hip/hip_bf16.h>
#include <math.h>

#define BB 4
#define VV 1024
#define HH 128
#define H2 64
#define EE 523776               // V*(V-1)/2
#define BE (BB * EE)            // 2095104
#define TPB (EE / 16)           // 32736 tiles per batch
#define NTILES (BE / 16)        // 130944
#define NTHR 256
#define NBLK 1024
#define NWAVE (NBLK * 4)        // 4096

typedef __attribute__((ext_vector_type(8))) short bf16x8;
typedef __attribute__((ext_vector_type(4))) float f32x4;
typedef __attribute__((ext_vector_type(4))) unsigned u32x4;

__device__ __forceinline__ short f2bf(float f) {
    __hip_bfloat16 h = __float2bfloat16(f);
    return *reinterpret_cast<short*>(&h);
}

// ONE v_perm_b32: pack two f32 into bf16x2 by truncation (lo -> low half).
__device__ __forceinline__ unsigned pkbf(float lo, float hi) {
    return __builtin_amdgcn_perm(__float_as_uint(hi), __float_as_uint(lo),
                                 0x07060302u);
}

__device__ __forceinline__ bf16x8 relu_pack(f32x4 a, f32x4 b) {
    u32x4 r;
    r[0] = pkbf(fmaxf(a[0], 0.f), fmaxf(a[1], 0.f));
    r[1] = pkbf(fmaxf(a[2], 0.f), fmaxf(a[3], 0.f));
    r[2] = pkbf(fmaxf(b[0], 0.f), fmaxf(b[1], 0.f));
    r[3] = pkbf(fmaxf(b[2], 0.f), fmaxf(b[3], 0.f));
    return __builtin_bit_cast(bf16x8, r);
}

// ---------------------------------------------------------------------------
// Round 11: occupancy fix. Model from R3-R10: MFMA A-operands live in AGPRs
// natively (no shuttle), so R3-R6's 128 persistent weight regs + ~90 working
// => ~220 unified regs => 2 waves/SIMD, latency-bound. R10 proved capping at
// 128 spills. Split instead: A2 (64 regs, MFMA-A-only -> AGPR) stays
// resident; A1 / w3-A3 / b2-Cinit stream from per-lane LDS frag tables
// (conflict-free ds_read_b128). L3 done as MFMA (A2 rows permuted so L2's D
// output IS L3's B-frag — verified correct in R10). Flat tile enumeration
// (balanced); single tile per iteration; bounds(256,3) = cap 170 (no spill),
// target actual ~114 regs -> 4 waves/SIMD.
// ---------------------------------------------------------------------------
__global__ __launch_bounds__(NTHR, 3) void edge_mlp_v11(
    const float* __restrict__ vertices,  // [4,1024,3]
    const float* __restrict__ W1,        // [6,128]
    const float* __restrict__ b1,        // [128]
    const float* __restrict__ W2,        // [128,64]
    const float* __restrict__ b2,        // [64]
    const float* __restrict__ W3,        // [64]
    const float* __restrict__ b3,        // [1]
    float* __restrict__ out)             // [BE probs][2*EE indices-as-float]
{
    // frag tables, 16B per lane, ids: 0..7 = A1[p][q1], 8..9 = A3[t]
    __shared__ __align__(16) bf16x8 wA[10 * 64];     // 10 KB
    __shared__ __align__(16) f32x4  wC[4 * 64];      // 4 KB  b2 C-init

    const int lane = threadIdx.x & 63;
    const int col  = lane & 15;          // edge slot (N dim everywhere)
    const int u    = lane >> 4;
    const int wid  = threadIdx.x >> 6;

    const f32x4 zero4 = {0.f, 0.f, 0.f, 0.f};

    // ---- A2 resident (MFMA-A-operand only -> AGPR-friendly) ----
    // A2r[mt*4+p] row m -> n2 = 32*(mt>>1) + 8*(m>>2) + 4*(mt&1) + (m&3),
    // element r -> k = h = 32p + 8u + r.  This row permutation makes L2's
    // D output land exactly in L3's B-frag slots (verified in R10).
    bf16x8 A2r[16];
#pragma unroll
    for (int mt = 0; mt < 4; ++mt) {
        const int n2 = 32 * (mt >> 1) + 8 * (col >> 2) + 4 * (mt & 1) + (col & 3);
#pragma unroll
        for (int p = 0; p < 4; ++p)
#pragma unroll
            for (int r = 0; r < 8; ++r)
                A2r[mt * 4 + p][r] = f2bf(W2[(32 * p + 8 * u + r) * H2 + n2]);
    }

    // ---- stage LDS frag tables (14 logical frags over 4 waves) ----
    for (int f = wid; f < 14; f += 4) {
        if (f < 8) {
            // A1: row m -> h = 32p + 8*(m>>2) + 4q1 + (m&3); elem r -> k=8u+r
            // (permutation makes L1's D output land in L2's B-frag slots)
            const int p = f >> 1, q1 = f & 1;
            const int h = 32 * p + 8 * (col >> 2) + 4 * q1 + (col & 3);
            bf16x8 a;
#pragma unroll
            for (int r = 0; r < 8; ++r) {
                const int k = 8 * u + r;
                float w = 0.0f;
                if (k < 6)       w = W1[k * HH + h];
                else if (k == 6) w = b1[h];
                a[r] = f2bf(w);
            }
            wA[f * 64 + lane] = a;
        } else if (f < 10) {
            // A3[t]: every row identical; elem r = W3[32t + 8u + r]
            const int t = f - 8;
            bf16x8 a;
#pragma unroll
            for (int r = 0; r < 8; ++r) a[r] = f2bf(W3[32 * t + 8 * u + r]);
            wA[f * 64 + lane] = a;
        } else {
            // cinit[mt]: q-component = b2[n2(mt, 4u+q)]
            const int mt = f - 10;
            f32x4 c;
#pragma unroll
            for (int q = 0; q < 4; ++q)
                c[q] = b2[32 * (mt >> 1) + 8 * u + 4 * (mt & 1) + q];
            wC[mt * 64 + lane] = c;
        }
    }
    const float b3v = b3[0];
    __syncthreads();

    const int gw = blockIdx.x * 4 + wid;

    for (int tt = gw; tt < NTILES; tt += NWAVE) {
        const int b  = tt / TPB;
        const int e0 = (tt - b * TPB) * 16;
        const int e  = e0 + col;

        // ---- decode e -> (i,j): reverse-triangular, exact f32 ----
        const int rr = EE - 1 - e;
        const float sq = sqrtf((float)(8 * rr + 1));
        int m = (int)(0.5f * (sq - 1.0f));
        if ((m + 1) * (m + 2) / 2 <= rr) ++m;
        if (m * (m + 1) / 2 > rr) --m;
        const int pp = rr - m * (m + 1) / 2;
        const int iv = VV - 2 - m;
        const int jv = VV - 1 - pp;

        // ---- feature B-frag (u!=0 lanes hold values that hit zero A1 rows) ----
        const float* pvi = vertices + (b * VV + iv) * 3;
        const float* pvj = vertices + (b * VV + jv) * 3;
        u32x4 fb;
        fb[0] = pkbf(pvi[0], pvi[1]);
        fb[1] = pkbf(pvi[2], pvj[0]);
        fb[2] = pkbf(pvj[1], pvj[2]);
        fb[3] = 0x00003F80u;                  // bf16(1.0) in k=6 carries b1
        const bf16x8 bfv = __builtin_bit_cast(bf16x8, fb);

        // ---- d2 init = b2 (LDS C-init frags) ----
        f32x4 d2_0 = wC[0 * 64 + lane];
        f32x4 d2_1 = wC[1 * 64 + lane];
        f32x4 d2_2 = wC[2 * 64 + lane];
        f32x4 d2_3 = wC[3 * 64 + lane];

        // ---- fused L1 -> relu/pack -> L2, per k-tile p ----
#pragma unroll
        for (int p = 0; p < 4; ++p) {
            const bf16x8 a1a = wA[(2 * p + 0) * 64 + lane];
            const bf16x8 a1b = wA[(2 * p + 1) * 64 + lane];
            const f32x4 dA = __builtin_amdgcn_mfma_f32_16x16x32_bf16(a1a, bfv, zero4, 0, 0, 0);
            const f32x4 dB = __builtin_amdgcn_mfma_f32_16x16x32_bf16(a1b, bfv, zero4, 0, 0, 0);
            const bf16x8 Bh = relu_pack(dA, dB);
            d2_0 = __builtin_amdgcn_mfma_f32_16x16x32_bf16(A2r[0 * 4 + p], Bh, d2_0, 0, 0, 0);
            d2_1 = __builtin_amdgcn_mfma_f32_16x16x32_bf16(A2r[1 * 4 + p], Bh, d2_1, 0, 0, 0);
            d2_2 = __builtin_amdgcn_mfma_f32_16x16x32_bf16(A2r[2 * 4 + p], Bh, d2_2, 0, 0, 0);
            d2_3 = __builtin_amdgcn_mfma_f32_16x16x32_bf16(A2r[3 * 4 + p], Bh, d2_3, 0, 0, 0);
        }

        // ---- L3 as MFMA: relu(d2) packs into L3 B-frags by construction ----
        const bf16x8 Bh3_0 = relu_pack(d2_0, d2_1);
        const bf16x8 Bh3_1 = relu_pack(d2_2, d2_3);
        const bf16x8 a30 = wA[8 * 64 + lane];
        const bf16x8 a31 = wA[9 * 64 + lane];
        f32x4 d3 = {b3v, b3v, b3v, b3v};
        d3 = __builtin_amdgcn_mfma_f32_16x16x32_bf16(a30, Bh3_0, d3, 0, 0, 0);
        d3 = __builtin_amdgcn_mfma_f32_16x16x32_bf16(a31, Bh3_1, d3, 0, 0, 0);
        // all D rows equal the w3 dot for edge col

        if (u == 0) {
            const float prob = __builtin_amdgcn_rcpf(1.0f + __expf(-d3[0]));
            out[tt * 16 + col] = prob;        // tt*16 == b*EE + e0
            if (b == 0)
                *(float2*)(&out[BE + 2 * e]) = make_float2((float)iv, (float)jv);
        }
    }
}

extern "C" void kernel_launch(void* const* d_in, const int* in_sizes, int n_in,
                              void* d_out, int out_size, void* d_ws, size_t ws_size,
                              hipStream_t stream) {
    const float* vertices = (const float*)d_in[0];
    const float* W1 = (const float*)d_in[1];
    const float* b1 = (const float*)d_in[2];
    const float* W2 = (const float*)d_in[3];
    const float* b2 = (const float*)d_in[4];
    const float* W3 = (const float*)d_in[5];
    const float* b3 = (const float*)d_in[6];
    float* out = (float*)d_out;

    edge_mlp_v11<<<NBLK, NTHR, 0, stream>>>(vertices, W1, b1, W2, b2, W3, b3, out);
}